// Round 16
// baseline (255.021 us; speedup 1.0000x reference)
//
#include <hip/hip_runtime.h>

// EnocoderBlock: x -> MHA -> +res,LN -> FFN -> +res,LN
// B=2, S=2048, D=1024, H=16, DFF=4096. All GEMMs in bf16 MFMA,
// fp32 accum; softmax/LN in fp32 (residual GEMM-branch and LN1 output
// carried in bf16 -- rounding ~0.4% rel on O(1) values, ~0.01 abs).
//
// R16 = R13/R15 best config + OCC=4 on FFN1 only (grid 1024 -> 4 blocks/CU
// exact, eliminating the 256-block tail round that OCC=3 leaves).

typedef float  f32x4   __attribute__((ext_vector_type(4)));
typedef float  f32x16  __attribute__((ext_vector_type(16)));
typedef __bf16 bf16x8  __attribute__((ext_vector_type(8)));
typedef __bf16 bf16x4  __attribute__((ext_vector_type(4)));

#define DEVI static __device__ __forceinline__

DEVI f32x4 mfma16(bf16x8 a, bf16x8 b, f32x4 c) {
    return __builtin_amdgcn_mfma_f32_16x16x32_bf16(a, b, c, 0, 0, 0);
}
DEVI f32x16 mfma32(bf16x8 a, bf16x8 b, f32x16 c) {
    return __builtin_amdgcn_mfma_f32_32x32x16_bf16(a, b, c, 0, 0, 0);
}

// async global->LDS, 16B per lane. lds dest must be wave-uniform (HW adds lane*16).
DEVI void gll16(const void* g, void* l) {
    __builtin_amdgcn_global_load_lds(
        (__attribute__((address_space(1))) void*)g,
        (__attribute__((address_space(3))) void*)l, 16, 0, 0);
}

DEVI __bf16 f2bf(float f) { return (__bf16)f; }

DEVI unsigned cvtpk_bf16(float a, float b) {
    unsigned d;
    asm("v_cvt_pk_bf16_f32 %0, %1, %2" : "=v"(d) : "v"(a), "v"(b));
    return d;
}
// v_permlane32_swap_b32 D,S: D[32..63] <-> S[0..31]
DEVI void permswap(unsigned& a, unsigned& b) {
    asm("v_permlane32_swap_b32 %0, %1" : "+v"(a), "+v"(b));
}
DEVI void permswapf(float& a, float& b) {
    asm("v_permlane32_swap_b32 %0, %1" : "+v"(a), "+v"(b));
}

// ---------------------------------------------------------------- utilities
// single launch: x + all 6 weight casts + mask nonzero scan. segment
// boundaries are multiples of 256 vec8 -> branches are wave-uniform.
__global__ __launch_bounds__(256) void cast_all_kernel(
    const float* __restrict__ x,
    const float* __restrict__ wq, const float* __restrict__ wk,
    const float* __restrict__ wv, const float* __restrict__ wo,
    const float* __restrict__ w1, const float* __restrict__ w2,
    const float* __restrict__ mask,
    __bf16* __restrict__ xb,
    __bf16* __restrict__ wqb, __bf16* __restrict__ wkb,
    __bf16* __restrict__ wvb, __bf16* __restrict__ wob,
    __bf16* __restrict__ w1b, __bf16* __restrict__ w2b,
    int* __restrict__ mflag) {
    int i = blockIdx.x * 256 + threadIdx.x;   // vec8 index
    if (i >= 2097152) {                        // mask-scan segment
        int off = i - 2097152;
        const float4* p = (const float4*)mask + (size_t)off * 2;
        float4 a = p[0], b = p[1];
        bool nz = a.x != 0.f || a.y != 0.f || a.z != 0.f || a.w != 0.f ||
                  b.x != 0.f || b.y != 0.f || b.z != 0.f || b.w != 0.f;
        if (__ballot(nz)) { if ((threadIdx.x & 63) == 0) atomicOr(mflag, 1); }
        return;
    }
    const float* src; __bf16* dst; int off;
    if      (i <  524288) { src = x;  dst = xb;  off = i; }
    else if (i <  655360) { src = wq; dst = wqb; off = i -  524288; }
    else if (i <  786432) { src = wk; dst = wkb; off = i -  655360; }
    else if (i <  917504) { src = wv; dst = wvb; off = i -  786432; }
    else if (i < 1048576) { src = wo; dst = wob; off = i -  917504; }
    else if (i < 1572864) { src = w1; dst = w1b; off = i - 1048576; }
    else                  { src = w2; dst = w2b; off = i - 1572864; }
    const float4* p = (const float4*)src + (size_t)off * 2;
    float4 a = p[0], b = p[1];
    bf16x8 o = { (__bf16)a.x, (__bf16)a.y, (__bf16)a.z, (__bf16)a.w,
                 (__bf16)b.x, (__bf16)b.y, (__bf16)b.z, (__bf16)b.w };
    *(bf16x8*)(dst + (size_t)off * 8) = o;
}

// ------------------------------------------------- residual add + LayerNorm
// XBF/YBF: X/Y operand dtype (0=f32, 1=bf16). outF (f32) and outB (bf16)
// each optional (nullptr skips).
template <int XBF, int YBF>
__global__ __launch_bounds__(256) void add_ln_kernel(
    const void* __restrict__ Xv, const void* __restrict__ Yv,
    const float* __restrict__ alphap, const float* __restrict__ gammap,
    float* __restrict__ outF, __bf16* __restrict__ outB) {
    const int tid = threadIdx.x, lane = tid & 63, wid = tid >> 6;
    const size_t base = (size_t)blockIdx.x * 1024 + tid * 4;
    float4 xv, yv;
    if (XBF) {
        bf16x4 t = *(const bf16x4*)((const __bf16*)Xv + base);
        xv.x = (float)t[0]; xv.y = (float)t[1]; xv.z = (float)t[2]; xv.w = (float)t[3];
    } else {
        xv = *(const float4*)((const float*)Xv + base);
    }
    if (YBF) {
        bf16x4 t = *(const bf16x4*)((const __bf16*)Yv + base);
        yv.x = (float)t[0]; yv.y = (float)t[1]; yv.z = (float)t[2]; yv.w = (float)t[3];
    } else {
        yv = *(const float4*)((const float*)Yv + base);
    }
    float vx = xv.x + yv.x, vy = xv.y + yv.y, vz = xv.z + yv.z, vw = xv.w + yv.w;
    float s = vx + vy + vz + vw;
    #pragma unroll
    for (int o = 32; o; o >>= 1) s += __shfl_xor(s, o);
    __shared__ float red[4];
    if (lane == 0) red[wid] = s;
    __syncthreads();
    float mean = (red[0] + red[1] + red[2] + red[3]) * (1.0f / 1024.0f);
    float dx = vx - mean, dy = vy - mean, dz = vz - mean, dw = vw - mean;
    float s2 = dx * dx + dy * dy + dz * dz + dw * dw;
    #pragma unroll
    for (int o = 32; o; o >>= 1) s2 += __shfl_xor(s2, o);
    __syncthreads();
    if (lane == 0) red[wid] = s2;
    __syncthreads();
    float var = (red[0] + red[1] + red[2] + red[3]) * (1.0f / 1024.0f);
    float rstd = rsqrtf(var + 1e-6f);
    float a = alphap[0], g = gammap[0];
    float4 o4 = { a * dx * rstd + g, a * dy * rstd + g, a * dz * rstd + g, a * dw * rstd + g };
    if (outF) *(float4*)&outF[base] = o4;
    if (outB) {
        bf16x4 ob = { f2bf(o4.x), f2bf(o4.y), f2bf(o4.z), f2bf(o4.w) };
        *(bf16x4*)&outB[base] = ob;
    }
}

// --------------------------------------------------------------- GEMM core
// C[m,n] = sum_k A[m,k]*W[n,k] + bias[n].  BM=128, BK=64, 4 waves (2x2).
// MODE 0: f32 out. MODE 1: relu -> bf16. MODE 2: bf16 (no relu).
// OCC: min blocks/CU bound (4 only for grids that divide 4/CU exactly).
template <int N, int K, int BN, int MODE, int OCC = 3>
__global__ __launch_bounds__(256, OCC) void gemm_bt_kernel(
    const __bf16* __restrict__ A, const __bf16* __restrict__ W,
    const float* __restrict__ bias, void* __restrict__ outp) {
    constexpr int WN = BN / 2;
    constexpr int NI = WN / 16;
    __shared__ __bf16 lsA[128 * 64];
    __shared__ __bf16 lsB[BN * 64];
    const int tid = threadIdx.x, wid = tid >> 6, lane = tid & 63;
    const int wr = wid >> 1, wc = wid & 1, l15 = lane & 15, hi = lane >> 4;
    const int m0 = blockIdx.y * 128, n0 = blockIdx.x * BN;
    f32x4 acc[4][NI] = {};
    for (int kt = 0; kt < K / 64; ++kt) {
        #pragma unroll
        for (int i = 0; i < 4; ++i) {
            int row = wid * 32 + i * 8 + (lane >> 3);
            gll16(A + (size_t)(m0 + row) * K + kt * 64 + ((lane & 7) ^ (row & 7)) * 8,
                  &lsA[(wid * 32 + i * 8) * 64]);
        }
        #pragma unroll
        for (int i = 0; i < BN / 32; ++i) {
            int row = wid * (BN / 4) + i * 8 + (lane >> 3);
            gll16(W + (size_t)(n0 + row) * K + kt * 64 + ((lane & 7) ^ (row & 7)) * 8,
                  &lsB[(wid * (BN / 4) + i * 8) * 64]);
        }
        __syncthreads();
        #pragma unroll
        for (int s = 0; s < 2; ++s) {
            bf16x8 af[4], bfv[NI];
            #pragma unroll
            for (int mi = 0; mi < 4; ++mi) {
                int row = wr * 64 + mi * 16 + l15;
                af[mi] = *(const bf16x8*)&lsA[row * 64 + (((s * 4 + hi) ^ (row & 7)) * 8)];
            }
            #pragma unroll
            for (int ni = 0; ni < NI; ++ni) {
                int row = wc * WN + ni * 16 + l15;
                bfv[ni] = *(const bf16x8*)&lsB[row * 64 + (((s * 4 + hi) ^ (row & 7)) * 8)];
            }
            #pragma unroll
            for (int mi = 0; mi < 4; ++mi)
                #pragma unroll
                for (int ni = 0; ni < NI; ++ni)
                    acc[mi][ni] = mfma16(af[mi], bfv[ni], acc[mi][ni]);
        }
        __syncthreads();
    }
    #pragma unroll
    for (int ni = 0; ni < NI; ++ni) {
        int col = n0 + wc * WN + ni * 16 + l15;
        float bv = bias[col];
        #pragma unroll
        for (int mi = 0; mi < 4; ++mi) {
            int rowb = m0 + wr * 64 + mi * 16 + hi * 4;
            #pragma unroll
            for (int r = 0; r < 4; ++r) {
                float v = acc[mi][ni][r] + bv;
                if (MODE == 0) {
                    ((float*)outp)[(size_t)(rowb + r) * N + col] = v;
                } else if (MODE == 1) {
                    v = fmaxf(v, 0.f);
                    ((__bf16*)outp)[(size_t)(rowb + r) * N + col] = f2bf(v);
                } else {
                    ((__bf16*)outp)[(size_t)(rowb + r) * N + col] = f2bf(v);
                }
            }
        }
    }
}

// QKV fused GEMM (N=K=1024, BN=128), z picks {Q,K,V}.
__global__ __launch_bounds__(256, 3) void gemm_qkv_kernel(
    const __bf16* __restrict__ A,
    const __bf16* __restrict__ wq, const __bf16* __restrict__ wk, const __bf16* __restrict__ wv,
    const float* __restrict__ bq, const float* __restrict__ bk, const float* __restrict__ bv,
    __bf16* __restrict__ q, __bf16* __restrict__ k, __bf16* __restrict__ vt) {
    constexpr int K = 1024;
    const int z = blockIdx.z;
    const __bf16* W = (z == 0) ? wq : (z == 1) ? wk : wv;
    const float* bias = (z == 0) ? bq : (z == 1) ? bk : bv;
    __shared__ __bf16 lsA[128 * 64];
    __shared__ __bf16 lsB[128 * 64];
    const int tid = threadIdx.x, wid = tid >> 6, lane = tid & 63;
    const int wr = wid >> 1, wc = wid & 1, l15 = lane & 15, hi = lane >> 4;
    const int m0 = blockIdx.y * 128, n0 = blockIdx.x * 128;
    f32x4 acc[4][4] = {};
    for (int kt = 0; kt < K / 64; ++kt) {
        #pragma unroll
        for (int i = 0; i < 4; ++i) {
            int row = wid * 32 + i * 8 + (lane >> 3);
            gll16(A + (size_t)(m0 + row) * K + kt * 64 + ((lane & 7) ^ (row & 7)) * 8,
                  &lsA[(wid * 32 + i * 8) * 64]);
            gll16(W + (size_t)(n0 + row) * K + kt * 64 + ((lane & 7) ^ (row & 7)) * 8,
                  &lsB[(wid * 32 + i * 8) * 64]);
        }
        __syncthreads();
        #pragma unroll
        for (int s = 0; s < 2; ++s) {
            bf16x8 af[4], bfv[4];
            #pragma unroll
            for (int mi = 0; mi < 4; ++mi) {
                int row = wr * 64 + mi * 16 + l15;
                af[mi] = *(const bf16x8*)&lsA[row * 64 + (((s * 4 + hi) ^ (row & 7)) * 8)];
            }
            #pragma unroll
            for (int ni = 0; ni < 4; ++ni) {
                int row = wc * 64 + ni * 16 + l15;
                bfv[ni] = *(const bf16x8*)&lsB[row * 64 + (((s * 4 + hi) ^ (row & 7)) * 8)];
            }
            #pragma unroll
            for (int mi = 0; mi < 4; ++mi)
                #pragma unroll
                for (int ni = 0; ni < 4; ++ni)
                    acc[mi][ni] = mfma16(af[mi], bfv[ni], acc[mi][ni]);
        }
        __syncthreads();
    }
    const float scale = (z == 0) ? 0.125f * 1.4426950408889634f : 1.0f;
    #pragma unroll
    for (int ni = 0; ni < 4; ++ni) {
        int col = n0 + wc * 64 + ni * 16 + l15;
        int h = col >> 6, dk = col & 63;
        float bvv = bias[col];
        #pragma unroll
        for (int mi = 0; mi < 4; ++mi) {
            int rowb = m0 + wr * 64 + mi * 16 + hi * 4;
            int b_ = rowb >> 11, sb = rowb & 2047;
            if (z < 2) {
                __bf16* dst = (z == 0) ? q : k;
                #pragma unroll
                for (int r = 0; r < 4; ++r)
                    dst[((size_t)(b_ * 16 + h) * 2048 + sb + r) * 64 + dk] =
                        f2bf((acc[mi][ni][r] + bvv) * scale);
            } else {
                bf16x4 o = { f2bf(acc[mi][ni][0] + bvv), f2bf(acc[mi][ni][1] + bvv),
                             f2bf(acc[mi][ni][2] + bvv), f2bf(acc[mi][ni][3] + bvv) };
                *(bf16x4*)&vt[((size_t)(b_ * 16 + h) * 64 + dk) * 2048 + sb] = o;
            }
        }
    }
}

// ---------------------------------------------------------- flash attention
// (best-measured version, 73.7us.) LDS-staged in-register flash with
// STATIC-MAX softmax. Grid 512: block = 128 q rows, 4 waves x 32 q,
// double-buffered 64-kv tiles. p = 2^(s-40): exact softmax after final
// normalize; overflow needs s>167, underflow s<-86; masked -inf scores
// correctly underflow to 0. Row-sum accumulated per-lane f32x16, combined
// once at the end. S^T = mfma32(K,Q); P->bf16 via v_cvt_pk +
// permlane32_swap; PV accumulates ctx^T = mfma32(VT,P).
__global__ __launch_bounds__(256, 2) void flash_attn_kernel(
    const __bf16* __restrict__ Q, const __bf16* __restrict__ Kx,
    const __bf16* __restrict__ VT, const float* __restrict__ mask,
    const int* __restrict__ mflag, __bf16* __restrict__ ctx) {
    __shared__ __bf16 Kl[2][64 * 64];   // [kv][dk], 128B rows, XOR-8 chunk swizzle
    __shared__ __bf16 Vl[2][64 * 64];   // [dk][kv], 128B rows, XOR-8 chunk swizzle
    const int lane = threadIdx.x & 63, wid = threadIdx.x >> 6;
    const int l31 = lane & 31, h = lane >> 5;
    const int id = blockIdx.x;
    const int xcd = id & 7, rest = id >> 3;
    const int qt = rest & 15;
    const int bh = (rest >> 4) * 8 + xcd;
    const int q0 = qt * 128 + wid * 32;

    bf16x8 qf[4];
    const size_t qrow = (size_t)bh * 2048 + q0 + l31;
    #pragma unroll
    for (int st = 0; st < 4; ++st)
        qf[st] = *(const bf16x8*)&Q[qrow * 64 + st * 16 + h * 8];

    const __bf16* kbase = Kx + (size_t)bh * 2048 * 64;   // [kv][64], 128B rows
    const __bf16* vbase = VT + (size_t)bh * 64 * 2048;   // [dk][2048], 4KB rows

    f32x16 c0 = {}, c1 = {};
    f32x16 lv = {};                    // per-lane partial row-sums (16 kv slots)
    const bool useMask = (*mflag != 0);

    const int r0 = wid * 16;
    const int rA = r0 + (lane >> 3);
    const int rB = rA + 8;
    const int cA = (lane & 7) ^ (rA & 7);
    const int cB = (lane & 7) ^ (rB & 7);

    auto stage = [&](int b, int t) {
        gll16(kbase + (size_t)(t * 64 + rA) * 64 + cA * 8, &Kl[b][r0 * 64]);
        gll16(kbase + (size_t)(t * 64 + rB) * 64 + cB * 8, &Kl[b][(r0 + 8) * 64]);
        gll16(vbase + (size_t)rA * 2048 + t * 64 + cA * 8, &Vl[b][r0 * 64]);
        gll16(vbase + (size_t)rB * 2048 + t * 64 + cB * 8, &Vl[b][(r0 + 8) * 64]);
    };

    stage(0, 0);
    __syncthreads();
    int cur = 0;

    for (int t = 0; t < 32; ++t) {
        const int tn = (t + 1 < 32) ? t + 1 : t;
        stage(cur ^ 1, tn);
        #pragma unroll
        for (int s = 0; s < 2; ++s) {
            const int krow = s * 32 + l31;
            f32x16 sc = {};
            __builtin_amdgcn_s_setprio(1);
            #pragma unroll
            for (int st = 0; st < 4; ++st) {
                bf16x8 kf = *(const bf16x8*)&Kl[cur][krow * 64 + (((st * 2 + h) ^ (krow & 7)) * 8)];
                sc = mfma32(kf, qf[st], sc);
            }
            __builtin_amdgcn_s_setprio(0);
            if (useMask) {
                #pragma unroll
                for (int r = 0; r < 16; ++r) {
                    int kv = t * 64 + s * 32 + (r & 3) + 8 * (r >> 2) + 4 * h;
                    sc[r] += mask[(size_t)(q0 + l31) * 2048 + kv] * 1.4426950408889634f;
                }
            }
            #pragma unroll
            for (int r = 0; r < 16; ++r) sc[r] = exp2f(sc[r] - 40.0f);
            lv += sc;
            unsigned w0 = cvtpk_bf16(sc[0], sc[1]),   w2 = cvtpk_bf16(sc[4], sc[5]);
            unsigned w1 = cvtpk_bf16(sc[2], sc[3]),   w3 = cvtpk_bf16(sc[6], sc[7]);
            permswap(w0, w2); permswap(w1, w3);
            unsigned w4 = cvtpk_bf16(sc[8], sc[9]),   w6 = cvtpk_bf16(sc[12], sc[13]);
            unsigned w5 = cvtpk_bf16(sc[10], sc[11]), w7 = cvtpk_bf16(sc[14], sc[15]);
            permswap(w4, w6); permswap(w5, w7);
            uint4 u0 = { w0, w1, w2, w3 }, u1 = { w4, w5, w6, w7 };
            bf16x8 pb0, pb1;
            __builtin_memcpy(&pb0, &u0, 16);
            __builtin_memcpy(&pb1, &u1, 16);
            const int vr0 = l31, vr1 = 32 + l31;
            bf16x8 v00 = *(const bf16x8*)&Vl[cur][vr0 * 64 + (((s * 4 + 0 + h) ^ (vr0 & 7)) * 8)];
            bf16x8 v01 = *(const bf16x8*)&Vl[cur][vr0 * 64 + (((s * 4 + 2 + h) ^ (vr0 & 7)) * 8)];
            bf16x8 v10 = *(const bf16x8*)&Vl[cur][vr1 * 64 + (((s * 4 + 0 + h) ^ (vr1 & 7)) * 8)];
            bf16x8 v11 = *(const bf16x8*)&Vl[cur][vr1 * 64 + (((s * 4 + 2 + h) ^ (vr1 & 7)) * 8)];
            __builtin_amdgcn_s_setprio(1);
            c0 = mfma32(v00, pb0, c0);
            c0 = mfma32(v01, pb1, c0);
            c1 = mfma32(v10, pb0, c1);
            c1 = mfma32(v11, pb1, c1);
            __builtin_amdgcn_s_setprio(0);
        }
        __syncthreads();
        cur ^= 1;
    }

    float y8[8], y4[4];
    #pragma unroll
    for (int r = 0; r < 8; ++r) y8[r] = lv[2 * r] + lv[2 * r + 1];
    #pragma unroll
    for (int r = 0; r < 4; ++r) y4[r] = y8[2 * r] + y8[2 * r + 1];
    float ls = (y4[0] + y4[1]) + (y4[2] + y4[3]);
    float la = ls, lb = ls;
    permswapf(la, lb);
    const float rinv = 1.0f / (la + lb);

    const int b_ = bh >> 4, h_ = bh & 15;
    const size_t obase = ((size_t)b_ * 2048 + q0 + l31) * 1024 + (size_t)h_ * 64;
    #pragma unroll
    for (int g = 0; g < 4; ++g) {
        bf16x4 o0 = { f2bf(c0[4 * g + 0] * rinv), f2bf(c0[4 * g + 1] * rinv),
                      f2bf(c0[4 * g + 2] * rinv), f2bf(c0[4 * g + 3] * rinv) };
        *(bf16x4*)&ctx[obase + g * 8 + h * 4] = o0;
        bf16x4 o1 = { f2bf(c1[4 * g + 0] * rinv), f2bf(c1[4 * g + 1] * rinv),
                      f2bf(c1[4 * g + 2] * rinv), f2bf(c1[4 * g + 3] * rinv) };
        *(bf16x4*)&ctx[obase + 32 + g * 8 + h * 4] = o1;
    }
}

// -------------------------------------------------------------------- launch
extern "C" void kernel_launch(void* const* d_in, const int* in_sizes, int n_in,
                              void* d_out, int out_size, void* d_ws, size_t ws_size,
                              hipStream_t stream) {
    const float* x     = (const float*)d_in[0];
    const float* mask  = (const float*)d_in[1];
    const float* wq    = (const float*)d_in[2];
    const float* bq    = (const float*)d_in[3];
    const float* wk    = (const float*)d_in[4];
    const float* bk    = (const float*)d_in[5];
    const float* wv    = (const float*)d_in[6];
    const float* bv    = (const float*)d_in[7];
    const float* wo    = (const float*)d_in[8];
    const float* bo    = (const float*)d_in[9];
    const float* w1    = (const float*)d_in[10];
    const float* b1    = (const float*)d_in[11];
    const float* w2    = (const float*)d_in[12];
    const float* b2    = (const float*)d_in[13];
    const float* alpha = (const float*)d_in[14];
    const float* gamma = (const float*)d_in[15];

    char* ws = (char*)d_ws;
    const size_t MB = 1u << 20;
    __bf16* xb    = (__bf16*)(ws + 0 * MB);     // 8M  x bf16 [4096,1024]
    __bf16* qb    = (__bf16*)(ws + 8 * MB);     // 8M  Q [B,H,S,DK] prescaled
    __bf16* kb    = (__bf16*)(ws + 16 * MB);    // 8M  K [B,H,S,DK]
    __bf16* vtb   = (__bf16*)(ws + 24 * MB);    // 8M  V^T [B,H,DK,S]
    __bf16* ctxb  = (__bf16*)(ws + 32 * MB);    // 8M  ctx [B,S,D]
    __bf16* wqb   = (__bf16*)(ws + 40 * MB);    // 2M
    __bf16* wkb   = (__bf16*)(ws + 42 * MB);    // 2M
    __bf16* wvb   = (__bf16*)(ws + 44 * MB);    // 2M
    __bf16* wob   = (__bf16*)(ws + 46 * MB);    // 2M
    __bf16* w1b   = (__bf16*)(ws + 48 * MB);    // 8M
    __bf16* w2b   = (__bf16*)(ws + 56 * MB);    // 8M
    __bf16* attnb = (__bf16*)(ws + 64 * MB);    // 8M  bf16 GEMM branch (WO / FFN2 out)
    __bf16* out1b = (__bf16*)(ws + 96 * MB);    // 8M  LN1 output (bf16)
    __bf16* hid   = (__bf16*)(ws + 104 * MB);   // 32M [4096,4096]
    int*    mflag = (int*)(ws + 136 * MB);
    if (ws_size < 136 * MB + 64) return;  // workspace too small -> loud failure

    hipMemsetAsync(mflag, 0, 4, stream);
    cast_all_kernel<<<10240, 256, 0, stream>>>(x, wq, wk, wv, wo, w1, w2, mask,
                                               xb, wqb, wkb, wvb, wob, w1b, w2b,
                                               mflag);

    gemm_qkv_kernel<<<dim3(8, 32, 3), 256, 0, stream>>>(xb, wqb, wkb, wvb, bq, bk, bv,
                                                        qb, kb, vtb);
    flash_attn_kernel<<<dim3(512), 256, 0, stream>>>(qb, kb, vtb, mask, mflag, ctxb);
    gemm_bt_kernel<1024, 1024, 64, 2><<<dim3(16, 32), 256, 0, stream>>>(ctxb, wob, bo, attnb);
    add_ln_kernel<0, 1><<<4096, 256, 0, stream>>>(x, attnb, alpha, gamma, nullptr, out1b);
    gemm_bt_kernel<4096, 1024, 128, 1, 4><<<dim3(32, 32), 256, 0, stream>>>(out1b, w1b, b1, hid);
    gemm_bt_kernel<1024, 4096, 64, 2><<<dim3(16, 32), 256, 0, stream>>>(hid, w2b, b2, attnb);
    add_ln_kernel<1, 1><<<4096, 256, 0, stream>>>(out1b, attnb, alpha, gamma, (float*)d_out, nullptr);
}

// Round 17
// 247.344 us; speedup vs baseline: 1.0310x; 1.0310x over previous
//
#include <hip/hip_runtime.h>

// EnocoderBlock: x -> MHA -> +res,LN -> FFN -> +res,LN
// B=2, S=2048, D=1024, H=16, DFF=4096. All GEMMs in bf16 MFMA,
// fp32 accum; softmax/LN in fp32 (residual GEMM-branch and LN1 output
// carried in bf16 -- rounding ~0.4% rel on O(1) values, ~0.01 abs).
//
// R17 = R15 best config + K-split x2 on WO and FFN2 (gridDim.z picks the
// K-half; each half writes its own bf16 buffer; residual LN does the
// 3-operand merge v = x + y1 + y2). Raises those GEMMs from 2 to 4
// blocks/CU without touching the proven sync structure.

typedef float  f32x4   __attribute__((ext_vector_type(4)));
typedef float  f32x16  __attribute__((ext_vector_type(16)));
typedef __bf16 bf16x8  __attribute__((ext_vector_type(8)));
typedef __bf16 bf16x4  __attribute__((ext_vector_type(4)));

#define DEVI static __device__ __forceinline__

DEVI f32x4 mfma16(bf16x8 a, bf16x8 b, f32x4 c) {
    return __builtin_amdgcn_mfma_f32_16x16x32_bf16(a, b, c, 0, 0, 0);
}
DEVI f32x16 mfma32(bf16x8 a, bf16x8 b, f32x16 c) {
    return __builtin_amdgcn_mfma_f32_32x32x16_bf16(a, b, c, 0, 0, 0);
}

// async global->LDS, 16B per lane. lds dest must be wave-uniform (HW adds lane*16).
DEVI void gll16(const void* g, void* l) {
    __builtin_amdgcn_global_load_lds(
        (__attribute__((address_space(1))) void*)g,
        (__attribute__((address_space(3))) void*)l, 16, 0, 0);
}

DEVI __bf16 f2bf(float f) { return (__bf16)f; }

DEVI unsigned cvtpk_bf16(float a, float b) {
    unsigned d;
    asm("v_cvt_pk_bf16_f32 %0, %1, %2" : "=v"(d) : "v"(a), "v"(b));
    return d;
}
// v_permlane32_swap_b32 D,S: D[32..63] <-> S[0..31]
DEVI void permswap(unsigned& a, unsigned& b) {
    asm("v_permlane32_swap_b32 %0, %1" : "+v"(a), "+v"(b));
}
DEVI void permswapf(float& a, float& b) {
    asm("v_permlane32_swap_b32 %0, %1" : "+v"(a), "+v"(b));
}

// ---------------------------------------------------------------- utilities
// single launch: x + all 6 weight casts + mask nonzero scan. segment
// boundaries are multiples of 256 vec8 -> branches are wave-uniform.
__global__ __launch_bounds__(256) void cast_all_kernel(
    const float* __restrict__ x,
    const float* __restrict__ wq, const float* __restrict__ wk,
    const float* __restrict__ wv, const float* __restrict__ wo,
    const float* __restrict__ w1, const float* __restrict__ w2,
    const float* __restrict__ mask,
    __bf16* __restrict__ xb,
    __bf16* __restrict__ wqb, __bf16* __restrict__ wkb,
    __bf16* __restrict__ wvb, __bf16* __restrict__ wob,
    __bf16* __restrict__ w1b, __bf16* __restrict__ w2b,
    int* __restrict__ mflag) {
    int i = blockIdx.x * 256 + threadIdx.x;   // vec8 index
    if (i >= 2097152) {                        // mask-scan segment
        int off = i - 2097152;
        const float4* p = (const float4*)mask + (size_t)off * 2;
        float4 a = p[0], b = p[1];
        bool nz = a.x != 0.f || a.y != 0.f || a.z != 0.f || a.w != 0.f ||
                  b.x != 0.f || b.y != 0.f || b.z != 0.f || b.w != 0.f;
        if (__ballot(nz)) { if ((threadIdx.x & 63) == 0) atomicOr(mflag, 1); }
        return;
    }
    const float* src; __bf16* dst; int off;
    if      (i <  524288) { src = x;  dst = xb;  off = i; }
    else if (i <  655360) { src = wq; dst = wqb; off = i -  524288; }
    else if (i <  786432) { src = wk; dst = wkb; off = i -  655360; }
    else if (i <  917504) { src = wv; dst = wvb; off = i -  786432; }
    else if (i < 1048576) { src = wo; dst = wob; off = i -  917504; }
    else if (i < 1572864) { src = w1; dst = w1b; off = i - 1048576; }
    else                  { src = w2; dst = w2b; off = i - 1572864; }
    const float4* p = (const float4*)src + (size_t)off * 2;
    float4 a = p[0], b = p[1];
    bf16x8 o = { (__bf16)a.x, (__bf16)a.y, (__bf16)a.z, (__bf16)a.w,
                 (__bf16)b.x, (__bf16)b.y, (__bf16)b.z, (__bf16)b.w };
    *(bf16x8*)(dst + (size_t)off * 8) = o;
}

// -------------------------------------- residual add + LayerNorm (3-input)
// v = X + Y1 + Y2; XBF: X dtype (0=f32, 1=bf16); Y1/Y2 bf16 (Y2 nullptr ok
// via NY template). outF (f32) and outB (bf16) each optional.
template <int XBF, int NY>
__global__ __launch_bounds__(256) void add_ln_kernel(
    const void* __restrict__ Xv, const __bf16* __restrict__ Y1,
    const __bf16* __restrict__ Y2,
    const float* __restrict__ alphap, const float* __restrict__ gammap,
    float* __restrict__ outF, __bf16* __restrict__ outB) {
    const int tid = threadIdx.x, lane = tid & 63, wid = tid >> 6;
    const size_t base = (size_t)blockIdx.x * 1024 + tid * 4;
    float4 xv;
    if (XBF) {
        bf16x4 t = *(const bf16x4*)((const __bf16*)Xv + base);
        xv.x = (float)t[0]; xv.y = (float)t[1]; xv.z = (float)t[2]; xv.w = (float)t[3];
    } else {
        xv = *(const float4*)((const float*)Xv + base);
    }
    bf16x4 t1 = *(const bf16x4*)(Y1 + base);
    float vx = xv.x + (float)t1[0], vy = xv.y + (float)t1[1];
    float vz = xv.z + (float)t1[2], vw = xv.w + (float)t1[3];
    if (NY == 2) {
        bf16x4 t2 = *(const bf16x4*)(Y2 + base);
        vx += (float)t2[0]; vy += (float)t2[1]; vz += (float)t2[2]; vw += (float)t2[3];
    }
    float s = vx + vy + vz + vw;
    #pragma unroll
    for (int o = 32; o; o >>= 1) s += __shfl_xor(s, o);
    __shared__ float red[4];
    if (lane == 0) red[wid] = s;
    __syncthreads();
    float mean = (red[0] + red[1] + red[2] + red[3]) * (1.0f / 1024.0f);
    float dx = vx - mean, dy = vy - mean, dz = vz - mean, dw = vw - mean;
    float s2 = dx * dx + dy * dy + dz * dz + dw * dw;
    #pragma unroll
    for (int o = 32; o; o >>= 1) s2 += __shfl_xor(s2, o);
    __syncthreads();
    if (lane == 0) red[wid] = s2;
    __syncthreads();
    float var = (red[0] + red[1] + red[2] + red[3]) * (1.0f / 1024.0f);
    float rstd = rsqrtf(var + 1e-6f);
    float a = alphap[0], g = gammap[0];
    float4 o4 = { a * dx * rstd + g, a * dy * rstd + g, a * dz * rstd + g, a * dw * rstd + g };
    if (outF) *(float4*)&outF[base] = o4;
    if (outB) {
        bf16x4 ob = { f2bf(o4.x), f2bf(o4.y), f2bf(o4.z), f2bf(o4.w) };
        *(bf16x4*)&outB[base] = ob;
    }
}

// --------------------------------------------------------------- GEMM core
// C[m,n] = sum_k A[m,k]*W[n,k] + bias[n].  BM=128, BK=64, 4 waves (2x2).
// MODE 0: f32 out. MODE 1: relu -> bf16. MODE 2: bf16 (no relu).
// OCC: min blocks/CU bound. KSPLIT: blockIdx.z picks a K-range; each half
// writes its own output plane (outp + half*M*N); bias applied in half 0 only.
template <int N, int K, int BN, int MODE, int OCC = 3, int KSPLIT = 1>
__global__ __launch_bounds__(256, OCC) void gemm_bt_kernel(
    const __bf16* __restrict__ A, const __bf16* __restrict__ W,
    const float* __restrict__ bias, void* __restrict__ outp) {
    constexpr int WN = BN / 2;
    constexpr int NI = WN / 16;
    constexpr int NTK = K / 64 / KSPLIT;
    __shared__ __bf16 lsA[128 * 64];
    __shared__ __bf16 lsB[BN * 64];
    const int tid = threadIdx.x, wid = tid >> 6, lane = tid & 63;
    const int wr = wid >> 1, wc = wid & 1, l15 = lane & 15, hi = lane >> 4;
    const int m0 = blockIdx.y * 128, n0 = blockIdx.x * BN;
    const int half = (KSPLIT > 1) ? blockIdx.z : 0;
    f32x4 acc[4][NI] = {};
    for (int kt = half * NTK; kt < half * NTK + NTK; ++kt) {
        #pragma unroll
        for (int i = 0; i < 4; ++i) {
            int row = wid * 32 + i * 8 + (lane >> 3);
            gll16(A + (size_t)(m0 + row) * K + kt * 64 + ((lane & 7) ^ (row & 7)) * 8,
                  &lsA[(wid * 32 + i * 8) * 64]);
        }
        #pragma unroll
        for (int i = 0; i < BN / 32; ++i) {
            int row = wid * (BN / 4) + i * 8 + (lane >> 3);
            gll16(W + (size_t)(n0 + row) * K + kt * 64 + ((lane & 7) ^ (row & 7)) * 8,
                  &lsB[(wid * (BN / 4) + i * 8) * 64]);
        }
        __syncthreads();
        #pragma unroll
        for (int s = 0; s < 2; ++s) {
            bf16x8 af[4], bfv[NI];
            #pragma unroll
            for (int mi = 0; mi < 4; ++mi) {
                int row = wr * 64 + mi * 16 + l15;
                af[mi] = *(const bf16x8*)&lsA[row * 64 + (((s * 4 + hi) ^ (row & 7)) * 8)];
            }
            #pragma unroll
            for (int ni = 0; ni < NI; ++ni) {
                int row = wc * WN + ni * 16 + l15;
                bfv[ni] = *(const bf16x8*)&lsB[row * 64 + (((s * 4 + hi) ^ (row & 7)) * 8)];
            }
            #pragma unroll
            for (int mi = 0; mi < 4; ++mi)
                #pragma unroll
                for (int ni = 0; ni < NI; ++ni)
                    acc[mi][ni] = mfma16(af[mi], bfv[ni], acc[mi][ni]);
        }
        __syncthreads();
    }
    const size_t plane = (size_t)half * (size_t)gridDim.y * 128 * N;
    #pragma unroll
    for (int ni = 0; ni < NI; ++ni) {
        int col = n0 + wc * WN + ni * 16 + l15;
        float bv = (half == 0) ? bias[col] : 0.f;
        #pragma unroll
        for (int mi = 0; mi < 4; ++mi) {
            int rowb = m0 + wr * 64 + mi * 16 + hi * 4;
            #pragma unroll
            for (int r = 0; r < 4; ++r) {
                float v = acc[mi][ni][r] + bv;
                if (MODE == 0) {
                    ((float*)outp)[plane + (size_t)(rowb + r) * N + col] = v;
                } else if (MODE == 1) {
                    v = fmaxf(v, 0.f);
                    ((__bf16*)outp)[plane + (size_t)(rowb + r) * N + col] = f2bf(v);
                } else {
                    ((__bf16*)outp)[plane + (size_t)(rowb + r) * N + col] = f2bf(v);
                }
            }
        }
    }
}

// QKV fused GEMM (N=K=1024, BN=128), z picks {Q,K,V}.
__global__ __launch_bounds__(256, 3) void gemm_qkv_kernel(
    const __bf16* __restrict__ A,
    const __bf16* __restrict__ wq, const __bf16* __restrict__ wk, const __bf16* __restrict__ wv,
    const float* __restrict__ bq, const float* __restrict__ bk, const float* __restrict__ bv,
    __bf16* __restrict__ q, __bf16* __restrict__ k, __bf16* __restrict__ vt) {
    constexpr int K = 1024;
    const int z = blockIdx.z;
    const __bf16* W = (z == 0) ? wq : (z == 1) ? wk : wv;
    const float* bias = (z == 0) ? bq : (z == 1) ? bk : bv;
    __shared__ __bf16 lsA[128 * 64];
    __shared__ __bf16 lsB[128 * 64];
    const int tid = threadIdx.x, wid = tid >> 6, lane = tid & 63;
    const int wr = wid >> 1, wc = wid & 1, l15 = lane & 15, hi = lane >> 4;
    const int m0 = blockIdx.y * 128, n0 = blockIdx.x * 128;
    f32x4 acc[4][4] = {};
    for (int kt = 0; kt < K / 64; ++kt) {
        #pragma unroll
        for (int i = 0; i < 4; ++i) {
            int row = wid * 32 + i * 8 + (lane >> 3);
            gll16(A + (size_t)(m0 + row) * K + kt * 64 + ((lane & 7) ^ (row & 7)) * 8,
                  &lsA[(wid * 32 + i * 8) * 64]);
            gll16(W + (size_t)(n0 + row) * K + kt * 64 + ((lane & 7) ^ (row & 7)) * 8,
                  &lsB[(wid * 32 + i * 8) * 64]);
        }
        __syncthreads();
        #pragma unroll
        for (int s = 0; s < 2; ++s) {
            bf16x8 af[4], bfv[4];
            #pragma unroll
            for (int mi = 0; mi < 4; ++mi) {
                int row = wr * 64 + mi * 16 + l15;
                af[mi] = *(const bf16x8*)&lsA[row * 64 + (((s * 4 + hi) ^ (row & 7)) * 8)];
            }
            #pragma unroll
            for (int ni = 0; ni < 4; ++ni) {
                int row = wc * 64 + ni * 16 + l15;
                bfv[ni] = *(const bf16x8*)&lsB[row * 64 + (((s * 4 + hi) ^ (row & 7)) * 8)];
            }
            #pragma unroll
            for (int mi = 0; mi < 4; ++mi)
                #pragma unroll
                for (int ni = 0; ni < 4; ++ni)
                    acc[mi][ni] = mfma16(af[mi], bfv[ni], acc[mi][ni]);
        }
        __syncthreads();
    }
    const float scale = (z == 0) ? 0.125f * 1.4426950408889634f : 1.0f;
    #pragma unroll
    for (int ni = 0; ni < 4; ++ni) {
        int col = n0 + wc * 64 + ni * 16 + l15;
        int h = col >> 6, dk = col & 63;
        float bvv = bias[col];
        #pragma unroll
        for (int mi = 0; mi < 4; ++mi) {
            int rowb = m0 + wr * 64 + mi * 16 + hi * 4;
            int b_ = rowb >> 11, sb = rowb & 2047;
            if (z < 2) {
                __bf16* dst = (z == 0) ? q : k;
                #pragma unroll
                for (int r = 0; r < 4; ++r)
                    dst[((size_t)(b_ * 16 + h) * 2048 + sb + r) * 64 + dk] =
                        f2bf((acc[mi][ni][r] + bvv) * scale);
            } else {
                bf16x4 o = { f2bf(acc[mi][ni][0] + bvv), f2bf(acc[mi][ni][1] + bvv),
                             f2bf(acc[mi][ni][2] + bvv), f2bf(acc[mi][ni][3] + bvv) };
                *(bf16x4*)&vt[((size_t)(b_ * 16 + h) * 64 + dk) * 2048 + sb] = o;
            }
        }
    }
}

// ---------------------------------------------------------- flash attention
// (best-measured version, 73.7us.) LDS-staged in-register flash with
// STATIC-MAX softmax. Grid 512: block = 128 q rows, 4 waves x 32 q,
// double-buffered 64-kv tiles. p = 2^(s-40): exact softmax after final
// normalize; overflow needs s>167, underflow s<-86; masked -inf scores
// correctly underflow to 0. Row-sum accumulated per-lane f32x16, combined
// once at the end. S^T = mfma32(K,Q); P->bf16 via v_cvt_pk +
// permlane32_swap; PV accumulates ctx^T = mfma32(VT,P).
__global__ __launch_bounds__(256, 2) void flash_attn_kernel(
    const __bf16* __restrict__ Q, const __bf16* __restrict__ Kx,
    const __bf16* __restrict__ VT, const float* __restrict__ mask,
    const int* __restrict__ mflag, __bf16* __restrict__ ctx) {
    __shared__ __bf16 Kl[2][64 * 64];   // [kv][dk], 128B rows, XOR-8 chunk swizzle
    __shared__ __bf16 Vl[2][64 * 64];   // [dk][kv], 128B rows, XOR-8 chunk swizzle
    const int lane = threadIdx.x & 63, wid = threadIdx.x >> 6;
    const int l31 = lane & 31, h = lane >> 5;
    const int id = blockIdx.x;
    const int xcd = id & 7, rest = id >> 3;
    const int qt = rest & 15;
    const int bh = (rest >> 4) * 8 + xcd;
    const int q0 = qt * 128 + wid * 32;

    bf16x8 qf[4];
    const size_t qrow = (size_t)bh * 2048 + q0 + l31;
    #pragma unroll
    for (int st = 0; st < 4; ++st)
        qf[st] = *(const bf16x8*)&Q[qrow * 64 + st * 16 + h * 8];

    const __bf16* kbase = Kx + (size_t)bh * 2048 * 64;   // [kv][64], 128B rows
    const __bf16* vbase = VT + (size_t)bh * 64 * 2048;   // [dk][2048], 4KB rows

    f32x16 c0 = {}, c1 = {};
    f32x16 lv = {};                    // per-lane partial row-sums (16 kv slots)
    const bool useMask = (*mflag != 0);

    const int r0 = wid * 16;
    const int rA = r0 + (lane >> 3);
    const int rB = rA + 8;
    const int cA = (lane & 7) ^ (rA & 7);
    const int cB = (lane & 7) ^ (rB & 7);

    auto stage = [&](int b, int t) {
        gll16(kbase + (size_t)(t * 64 + rA) * 64 + cA * 8, &Kl[b][r0 * 64]);
        gll16(kbase + (size_t)(t * 64 + rB) * 64 + cB * 8, &Kl[b][(r0 + 8) * 64]);
        gll16(vbase + (size_t)rA * 2048 + t * 64 + cA * 8, &Vl[b][r0 * 64]);
        gll16(vbase + (size_t)rB * 2048 + t * 64 + cB * 8, &Vl[b][(r0 + 8) * 64]);
    };

    stage(0, 0);
    __syncthreads();
    int cur = 0;

    for (int t = 0; t < 32; ++t) {
        const int tn = (t + 1 < 32) ? t + 1 : t;
        stage(cur ^ 1, tn);
        #pragma unroll
        for (int s = 0; s < 2; ++s) {
            const int krow = s * 32 + l31;
            f32x16 sc = {};
            __builtin_amdgcn_s_setprio(1);
            #pragma unroll
            for (int st = 0; st < 4; ++st) {
                bf16x8 kf = *(const bf16x8*)&Kl[cur][krow * 64 + (((st * 2 + h) ^ (krow & 7)) * 8)];
                sc = mfma32(kf, qf[st], sc);
            }
            __builtin_amdgcn_s_setprio(0);
            if (useMask) {
                #pragma unroll
                for (int r = 0; r < 16; ++r) {
                    int kv = t * 64 + s * 32 + (r & 3) + 8 * (r >> 2) + 4 * h;
                    sc[r] += mask[(size_t)(q0 + l31) * 2048 + kv] * 1.4426950408889634f;
                }
            }
            #pragma unroll
            for (int r = 0; r < 16; ++r) sc[r] = exp2f(sc[r] - 40.0f);
            lv += sc;
            unsigned w0 = cvtpk_bf16(sc[0], sc[1]),   w2 = cvtpk_bf16(sc[4], sc[5]);
            unsigned w1 = cvtpk_bf16(sc[2], sc[3]),   w3 = cvtpk_bf16(sc[6], sc[7]);
            permswap(w0, w2); permswap(w1, w3);
            unsigned w4 = cvtpk_bf16(sc[8], sc[9]),   w6 = cvtpk_bf16(sc[12], sc[13]);
            unsigned w5 = cvtpk_bf16(sc[10], sc[11]), w7 = cvtpk_bf16(sc[14], sc[15]);
            permswap(w4, w6); permswap(w5, w7);
            uint4 u0 = { w0, w1, w2, w3 }, u1 = { w4, w5, w6, w7 };
            bf16x8 pb0, pb1;
            __builtin_memcpy(&pb0, &u0, 16);
            __builtin_memcpy(&pb1, &u1, 16);
            const int vr0 = l31, vr1 = 32 + l31;
            bf16x8 v00 = *(const bf16x8*)&Vl[cur][vr0 * 64 + (((s * 4 + 0 + h) ^ (vr0 & 7)) * 8)];
            bf16x8 v01 = *(const bf16x8*)&Vl[cur][vr0 * 64 + (((s * 4 + 2 + h) ^ (vr0 & 7)) * 8)];
            bf16x8 v10 = *(const bf16x8*)&Vl[cur][vr1 * 64 + (((s * 4 + 0 + h) ^ (vr1 & 7)) * 8)];
            bf16x8 v11 = *(const bf16x8*)&Vl[cur][vr1 * 64 + (((s * 4 + 2 + h) ^ (vr1 & 7)) * 8)];
            __builtin_amdgcn_s_setprio(1);
            c0 = mfma32(v00, pb0, c0);
            c0 = mfma32(v01, pb1, c0);
            c1 = mfma32(v10, pb0, c1);
            c1 = mfma32(v11, pb1, c1);
            __builtin_amdgcn_s_setprio(0);
        }
        __syncthreads();
        cur ^= 1;
    }

    float y8[8], y4[4];
    #pragma unroll
    for (int r = 0; r < 8; ++r) y8[r] = lv[2 * r] + lv[2 * r + 1];
    #pragma unroll
    for (int r = 0; r < 4; ++r) y4[r] = y8[2 * r] + y8[2 * r + 1];
    float ls = (y4[0] + y4[1]) + (y4[2] + y4[3]);
    float la = ls, lb = ls;
    permswapf(la, lb);
    const float rinv = 1.0f / (la + lb);

    const int b_ = bh >> 4, h_ = bh & 15;
    const size_t obase = ((size_t)b_ * 2048 + q0 + l31) * 1024 + (size_t)h_ * 64;
    #pragma unroll
    for (int g = 0; g < 4; ++g) {
        bf16x4 o0 = { f2bf(c0[4 * g + 0] * rinv), f2bf(c0[4 * g + 1] * rinv),
                      f2bf(c0[4 * g + 2] * rinv), f2bf(c0[4 * g + 3] * rinv) };
        *(bf16x4*)&ctx[obase + g * 8 + h * 4] = o0;
        bf16x4 o1 = { f2bf(c1[4 * g + 0] * rinv), f2bf(c1[4 * g + 1] * rinv),
                      f2bf(c1[4 * g + 2] * rinv), f2bf(c1[4 * g + 3] * rinv) };
        *(bf16x4*)&ctx[obase + 32 + g * 8 + h * 4] = o1;
    }
}

// -------------------------------------------------------------------- launch
extern "C" void kernel_launch(void* const* d_in, const int* in_sizes, int n_in,
                              void* d_out, int out_size, void* d_ws, size_t ws_size,
                              hipStream_t stream) {
    const float* x     = (const float*)d_in[0];
    const float* mask  = (const float*)d_in[1];
    const float* wq    = (const float*)d_in[2];
    const float* bq    = (const float*)d_in[3];
    const float* wk    = (const float*)d_in[4];
    const float* bk    = (const float*)d_in[5];
    const float* wv    = (const float*)d_in[6];
    const float* bv    = (const float*)d_in[7];
    const float* wo    = (const float*)d_in[8];
    const float* bo    = (const float*)d_in[9];
    const float* w1    = (const float*)d_in[10];
    const float* b1    = (const float*)d_in[11];
    const float* w2    = (const float*)d_in[12];
    const float* b2    = (const float*)d_in[13];
    const float* alpha = (const float*)d_in[14];
    const float* gamma = (const float*)d_in[15];

    char* ws = (char*)d_ws;
    const size_t MB = 1u << 20;
    __bf16* xb    = (__bf16*)(ws + 0 * MB);     // 8M  x bf16 [4096,1024]
    __bf16* qb    = (__bf16*)(ws + 8 * MB);     // 8M  Q [B,H,S,DK] prescaled
    __bf16* kb    = (__bf16*)(ws + 16 * MB);    // 8M  K [B,H,S,DK]
    __bf16* vtb   = (__bf16*)(ws + 24 * MB);    // 8M  V^T [B,H,DK,S]
    __bf16* ctxb  = (__bf16*)(ws + 32 * MB);    // 8M  ctx [B,S,D]
    __bf16* wqb   = (__bf16*)(ws + 40 * MB);    // 2M
    __bf16* wkb   = (__bf16*)(ws + 42 * MB);    // 2M
    __bf16* wvb   = (__bf16*)(ws + 44 * MB);    // 2M
    __bf16* wob   = (__bf16*)(ws + 46 * MB);    // 2M
    __bf16* w1b   = (__bf16*)(ws + 48 * MB);    // 8M
    __bf16* w2b   = (__bf16*)(ws + 56 * MB);    // 8M
    __bf16* attnb = (__bf16*)(ws + 64 * MB);    // 16M: two 8M K-split planes
    __bf16* attnb2= (__bf16*)(ws + 72 * MB);    //   (plane 1 = attnb + 8M)
    __bf16* out1b = (__bf16*)(ws + 96 * MB);    // 8M  LN1 output (bf16)
    __bf16* hid   = (__bf16*)(ws + 104 * MB);   // 32M [4096,4096]
    int*    mflag = (int*)(ws + 136 * MB);
    if (ws_size < 136 * MB + 64) return;  // workspace too small -> loud failure

    hipMemsetAsync(mflag, 0, 4, stream);
    cast_all_kernel<<<10240, 256, 0, stream>>>(x, wq, wk, wv, wo, w1, w2, mask,
                                               xb, wqb, wkb, wvb, wob, w1b, w2b,
                                               mflag);

    gemm_qkv_kernel<<<dim3(8, 32, 3), 256, 0, stream>>>(xb, wqb, wkb, wvb, bq, bk, bv,
                                                        qb, kb, vtb);
    flash_attn_kernel<<<dim3(512), 256, 0, stream>>>(qb, kb, vtb, mask, mflag, ctxb);
    // WO: K-split x2 (z picks K-half; planes attnb / attnb2), 1024 blocks.
    gemm_bt_kernel<1024, 1024, 64, 2, 4, 2><<<dim3(16, 32, 2), 256, 0, stream>>>(
        ctxb, wob, bo, attnb);
    add_ln_kernel<0, 2><<<4096, 256, 0, stream>>>(x, attnb, attnb2, alpha, gamma,
                                                  nullptr, out1b);
    gemm_bt_kernel<4096, 1024, 128, 1><<<dim3(32, 32), 256, 0, stream>>>(out1b, w1b, b1, hid);
    // FFN2: K-split x2, 1024 blocks.
    gemm_bt_kernel<1024, 4096, 64, 2, 4, 2><<<dim3(16, 32, 2), 256, 0, stream>>>(
        hid, w2b, b2, attnb);
    add_ln_kernel<1, 2><<<4096, 256, 0, stream>>>(out1b, attnb, attnb2, alpha, gamma,
                                                  (float*)d_out, nullptr);
}